// Round 2
// baseline (301.038 us; speedup 1.0000x reference)
//
#include <hip/hip_runtime.h>

// Problem constants
#define DIMC 256
#define BSZ  32
#define MDIM 2048
#define NDIM 2048

#define KVP_STRIDE ((size_t)BSZ * DIMC * DIMC)  // one split-K partial, in shorts

typedef __attribute__((ext_vector_type(8))) short bf16x8;   // 8 bf16 (4 VGPRs)
typedef __attribute__((ext_vector_type(4))) float f32x4;    // MFMA acc

static __device__ __forceinline__ unsigned short f2bf(float x) {
  unsigned int u = __float_as_uint(x);
  u += 0x7fffu + ((u >> 16) & 1u);          // round-to-nearest-even
  return (unsigned short)(u >> 16);
}
static __device__ __forceinline__ float bf2f(unsigned short h) {
  return __uint_as_float(((unsigned int)h) << 16);
}
// HW packed fp32->bf16 (RNE): low short = lo, high short = hi.
static __device__ __forceinline__ unsigned int cvt_pk_bf16(float lo, float hi) {
  unsigned int r;
  asm("v_cvt_pk_bf16_f32 %0, %1, %2" : "=v"(r) : "v"(lo), "v"(hi));
  return r;
}

// ---------------------------------------------------------------------------
// prep: Wt[e][c] = bf16(W[c][e]) ; zero rowsum
// ---------------------------------------------------------------------------
__global__ __launch_bounds__(256) void prep_kernel(
    const float* __restrict__ W, unsigned short* __restrict__ Wt,
    float* __restrict__ rowsum) {
  const int e = blockIdx.x, c = threadIdx.x;
  Wt[e * 256 + c] = f2bf(W[c * 256 + e]);
  if (e < 32) rowsum[e * 256 + c] = 0.f;   // rowsum[b][e] layout, b=e here
}

// ---------------------------------------------------------------------------
// phi_q[b][m][e] = relu(sum_c query[b][c][m] * Wt[e][c]) / 16   bf16, e-contig
// 128(m) x 128(e) tile. A=query transpose-staged; B=Wt natural.
// ---------------------------------------------------------------------------
__global__ __launch_bounds__(256) void phiq_kernel(
    const float* __restrict__ query, const unsigned short* __restrict__ Wt,
    unsigned short* __restrict__ phi_q) {
  __shared__ unsigned short As[128 * 40];  // [m][c], stride 40 bf16 = 80 B
  __shared__ unsigned short Bs[128 * 40];  // [e][c]
  const int b = blockIdx.z;
  const int m0 = blockIdx.x * 128;
  const int e0 = blockIdx.y * 128;
  const int t = threadIdx.x;
  const int lane = t & 63, wave = t >> 6;
  const int wr = wave >> 1, wc = wave & 1;
  const int q = lane >> 4, l15 = lane & 15;
  const float* qb = query + (size_t)b * DIMC * MDIM;
  f32x4 acc[4][4];
#pragma unroll
  for (int i = 0; i < 4; ++i)
#pragma unroll
    for (int j = 0; j < 4; ++j) acc[i][j] = (f32x4){0.f, 0.f, 0.f, 0.f};

  const int brow = t >> 2, bc8 = (t & 3) << 3;
  const int midx = t & 127, ch = (t >> 7) << 4;

  for (int k0 = 0; k0 < DIMC; k0 += 32) {
    __syncthreads();
    // stage A: query[c][m] -> As[m][c], packed HW cvt
    {
      const float* src = qb + (size_t)(k0 + ch) * MDIM + m0 + midx;
      float v[16];
#pragma unroll
      for (int i = 0; i < 16; ++i) v[i] = src[(size_t)i * MDIM];
      unsigned int w[8];
#pragma unroll
      for (int i = 0; i < 8; ++i) w[i] = cvt_pk_bf16(v[2 * i], v[2 * i + 1]);
      *(uint4*)&As[midx * 40 + ch] = *(const uint4*)&w[0];
      *(uint4*)&As[midx * 40 + ch + 8] = *(const uint4*)&w[4];
    }
    // stage B: Wt rows e0..e0+127 (natural bf16, 16B loads)
    {
      uint4 v0 = *(const uint4*)(Wt + (size_t)(e0 + brow) * 256 + k0 + bc8);
      uint4 v1 = *(const uint4*)(Wt + (size_t)(e0 + brow + 64) * 256 + k0 + bc8);
      *(uint4*)&Bs[brow * 40 + bc8] = v0;
      *(uint4*)&Bs[(brow + 64) * 40 + bc8] = v1;
    }
    __syncthreads();
    bf16x8 a[4], bv[4];
#pragma unroll
    for (int i = 0; i < 4; ++i)
      a[i] = *(const bf16x8*)&As[(wr * 64 + i * 16 + l15) * 40 + q * 8];
#pragma unroll
    for (int j = 0; j < 4; ++j)
      bv[j] = *(const bf16x8*)&Bs[(wc * 64 + j * 16 + l15) * 40 + q * 8];
#pragma unroll
    for (int i = 0; i < 4; ++i)
#pragma unroll
      for (int j = 0; j < 4; ++j)
        acc[i][j] =
            __builtin_amdgcn_mfma_f32_16x16x32_bf16(a[i], bv[j], acc[i][j], 0, 0, 0);
  }
  unsigned short* dst = phi_q + (size_t)b * MDIM * DIMC;
#pragma unroll
  for (int i = 0; i < 4; ++i)
#pragma unroll
    for (int j = 0; j < 4; ++j) {
      const int e = e0 + wc * 64 + j * 16 + l15;
#pragma unroll
      for (int r = 0; r < 4; ++r) {
        const int m = m0 + wr * 64 + i * 16 + q * 4 + r;
        float v = acc[i][j][r];
        v = v > 0.f ? v * 0.0625f : 0.f;
        dst[(size_t)m * DIMC + e] = f2bf(v);
      }
    }
}

// ---------------------------------------------------------------------------
// phi_k[b][e][n] = relu(sum_c Wt[e][c] * key[b][c][n])   bf16 out, n-contig
// + fused rowsum[b][e] += sum_n phi_k (atomicAdd, fp32 pre-rounding values)
// ---------------------------------------------------------------------------
__global__ __launch_bounds__(256) void phik_kernel(
    const float* __restrict__ key, const unsigned short* __restrict__ Wt,
    unsigned short* __restrict__ phi_k, float* __restrict__ rowsum) {
  __shared__ unsigned short As[128 * 40];  // [e][c]
  __shared__ unsigned short Bs[128 * 40];  // [n][c]
  const int b = blockIdx.z;
  const int n0 = blockIdx.x * 128;
  const int e0 = blockIdx.y * 128;
  const int t = threadIdx.x;
  const int lane = t & 63, wave = t >> 6;
  const int wr = wave >> 1, wc = wave & 1;
  const int q = lane >> 4, l15 = lane & 15;
  const float* keyb = key + (size_t)b * DIMC * NDIM;
  f32x4 acc[4][4];
#pragma unroll
  for (int i = 0; i < 4; ++i)
#pragma unroll
    for (int j = 0; j < 4; ++j) acc[i][j] = (f32x4){0.f, 0.f, 0.f, 0.f};

  const int arow = t >> 2, ac8 = (t & 3) << 3;
  const int nidx = t & 127, ch = (t >> 7) << 4;

  for (int k0 = 0; k0 < DIMC; k0 += 32) {
    __syncthreads();
    // stage A: Wt rows e0..e0+127 (natural bf16)
    {
      uint4 v0 = *(const uint4*)(Wt + (size_t)(e0 + arow) * 256 + k0 + ac8);
      uint4 v1 = *(const uint4*)(Wt + (size_t)(e0 + arow + 64) * 256 + k0 + ac8);
      *(uint4*)&As[arow * 40 + ac8] = v0;
      *(uint4*)&As[(arow + 64) * 40 + ac8] = v1;
    }
    // stage B: key[c][n] -> Bs[n][c], packed HW cvt
    {
      const float* src = keyb + (size_t)(k0 + ch) * NDIM + n0 + nidx;
      float v[16];
#pragma unroll
      for (int i = 0; i < 16; ++i) v[i] = src[(size_t)i * NDIM];
      unsigned int w[8];
#pragma unroll
      for (int i = 0; i < 8; ++i) w[i] = cvt_pk_bf16(v[2 * i], v[2 * i + 1]);
      *(uint4*)&Bs[nidx * 40 + ch] = *(const uint4*)&w[0];
      *(uint4*)&Bs[nidx * 40 + ch + 8] = *(const uint4*)&w[4];
    }
    __syncthreads();
    bf16x8 a[4], bv[4];
#pragma unroll
    for (int i = 0; i < 4; ++i)
      a[i] = *(const bf16x8*)&As[(wr * 64 + i * 16 + l15) * 40 + q * 8];
#pragma unroll
    for (int j = 0; j < 4; ++j)
      bv[j] = *(const bf16x8*)&Bs[(wc * 64 + j * 16 + l15) * 40 + q * 8];
#pragma unroll
    for (int i = 0; i < 4; ++i)
#pragma unroll
      for (int j = 0; j < 4; ++j)
        acc[i][j] =
            __builtin_amdgcn_mfma_f32_16x16x32_bf16(a[i], bv[j], acc[i][j], 0, 0, 0);
  }
  unsigned short* dst = phi_k + (size_t)b * DIMC * NDIM;
#pragma unroll
  for (int i = 0; i < 4; ++i)
#pragma unroll
    for (int r = 0; r < 4; ++r) {
      const int e = e0 + wr * 64 + i * 16 + q * 4 + r;
      float s = 0.f;
#pragma unroll
      for (int j = 0; j < 4; ++j) {
        float v = acc[i][j][r];
        v = v > 0.f ? v : 0.f;
        const int n = n0 + wc * 64 + j * 16 + l15;
        dst[(size_t)e * NDIM + n] = f2bf(v);
        s += v;
      }
      // reduce across the 16 l15 lanes (same e within this wave)
#pragma unroll
      for (int m = 1; m < 16; m <<= 1) s += __shfl_xor(s, m, 64);
      if (l15 == 0) atomicAdd(&rowsum[b * DIMC + e], s);
    }
}

// ---------------------------------------------------------------------------
// kv partials: kvp[ks][b][d][e] = sum_{n in ks-th half} value[b][d][n]*phi_k[b][e][n]
// split-K x2, 128(d) x 128(e) tile per block, BK=64. bf16 partial output.
// grid (2,2,64) = 256 blocks, 1/CU.
// ---------------------------------------------------------------------------
__global__ __launch_bounds__(256) void kv_kernel(
    const float* __restrict__ value, const unsigned short* __restrict__ phi_k,
    unsigned short* __restrict__ kvp) {
  __shared__ unsigned short As[128 * 72];  // [d][n], stride 72 bf16 = 144 B
  __shared__ unsigned short Bs[128 * 72];  // [e][n]
  const int b = blockIdx.z >> 1, ks = blockIdx.z & 1;
  const int d0 = blockIdx.x * 128, e0 = blockIdx.y * 128;
  const int t = threadIdx.x;
  const int lane = t & 63, wave = t >> 6;
  const int wr = wave >> 1, wc = wave & 1;
  const int q = lane >> 4, l15 = lane & 15;
  f32x4 acc[4][4];
#pragma unroll
  for (int i = 0; i < 4; ++i)
#pragma unroll
    for (int j = 0; j < 4; ++j) acc[i][j] = (f32x4){0.f, 0.f, 0.f, 0.f};

  const int row = t >> 2;
  const int c4 = (t & 3) << 2;  // float col base
  const int c8 = (t & 3) << 3;  // short col base

  const float* asrc0 = value + ((size_t)b * DIMC + d0 + row) * NDIM;
  const float* asrc1 = asrc0 + (size_t)64 * NDIM;
  const unsigned short* bsrc0 = phi_k + ((size_t)b * DIMC + e0 + row) * NDIM;
  const unsigned short* bsrc1 = bsrc0 + (size_t)64 * NDIM;

  const int nbeg = ks * (NDIM / 2);
  for (int n0 = nbeg; n0 < nbeg + NDIM / 2; n0 += 64) {
    __syncthreads();
    // stage A: value fp32 -> bf16, packed cvt
#pragma unroll
    for (int i = 0; i < 4; ++i) {
      float4 f0 = *(const float4*)(asrc0 + n0 + c4 + i * 16);
      float4 f1 = *(const float4*)(asrc1 + n0 + c4 + i * 16);
      uint2 w0, w1;
      w0.x = cvt_pk_bf16(f0.x, f0.y); w0.y = cvt_pk_bf16(f0.z, f0.w);
      w1.x = cvt_pk_bf16(f1.x, f1.y); w1.y = cvt_pk_bf16(f1.z, f1.w);
      *(uint2*)&As[row * 72 + c4 + i * 16] = w0;
      *(uint2*)&As[(row + 64) * 72 + c4 + i * 16] = w1;
    }
    // stage B: phi_k bf16 natural
#pragma unroll
    for (int i = 0; i < 2; ++i) {
      uint4 p0 = *(const uint4*)(bsrc0 + n0 + c8 + i * 32);
      uint4 p1 = *(const uint4*)(bsrc1 + n0 + c8 + i * 32);
      *(uint4*)&Bs[row * 72 + c8 + i * 32] = p0;
      *(uint4*)&Bs[(row + 64) * 72 + c8 + i * 32] = p1;
    }
    __syncthreads();
#pragma unroll
    for (int kk = 0; kk < 64; kk += 32) {
      bf16x8 a[4], bv[4];
#pragma unroll
      for (int i = 0; i < 4; ++i)
        a[i] = *(const bf16x8*)&As[(wr * 64 + i * 16 + l15) * 72 + kk + q * 8];
#pragma unroll
      for (int j = 0; j < 4; ++j)
        bv[j] = *(const bf16x8*)&Bs[(wc * 64 + j * 16 + l15) * 72 + kk + q * 8];
#pragma unroll
      for (int i = 0; i < 4; ++i)
#pragma unroll
        for (int j = 0; j < 4; ++j)
          acc[i][j] = __builtin_amdgcn_mfma_f32_16x16x32_bf16(a[i], bv[j],
                                                              acc[i][j], 0, 0, 0);
    }
  }
  unsigned short* dst = kvp + (size_t)ks * KVP_STRIDE + (size_t)b * DIMC * DIMC;
#pragma unroll
  for (int i = 0; i < 4; ++i)
#pragma unroll
    for (int j = 0; j < 4; ++j) {
      const int e = e0 + wc * 64 + j * 16 + l15;
#pragma unroll
      for (int r = 0; r < 4; ++r) {
        const int d = d0 + wr * 64 + i * 16 + q * 4 + r;
        dst[(size_t)d * DIMC + e] = f2bf(acc[i][j][r]);
      }
    }
}

// ---------------------------------------------------------------------------
// out[b][d][m] = scale[b][m] * sum_e kv[d][e] * phi_q[m][e]   fp32 out
// kv = sum of 2 bf16 split-K partials (summed during staging).
// scale computed in-kernel: running dot of phi_q rows with LDS-resident rowsum.
// ---------------------------------------------------------------------------
__global__ __launch_bounds__(256) void out_kernel(
    const unsigned short* __restrict__ kvp,
    const unsigned short* __restrict__ phi_q,
    const float* __restrict__ rowsum, float* __restrict__ out) {
  __shared__ unsigned short As[128 * 40];  // [d][e]
  __shared__ unsigned short Bs[128 * 40];  // [m][e]
  __shared__ float rs_lds[256];
  __shared__ float red[512];
  __shared__ float scl[128];
  const int b = blockIdx.z;
  const int m0 = blockIdx.x * 128;
  const int d0 = blockIdx.y * 128;
  const int t = threadIdx.x;
  const int lane = t & 63, wave = t >> 6;
  const int wr = wave >> 1, wc = wave & 1;
  const int q = lane >> 4, l15 = lane & 15;

  rs_lds[t] = rowsum[b * DIMC + t];

  f32x4 acc[4][4];
#pragma unroll
  for (int i = 0; i < 4; ++i)
#pragma unroll
    for (int j = 0; j < 4; ++j) acc[i][j] = (f32x4){0.f, 0.f, 0.f, 0.f};

  const int row = t >> 2, c8 = (t & 3) << 3;
  const unsigned short* a0 = kvp + ((size_t)b * DIMC + d0 + row) * DIMC + c8;
  const unsigned short* a1 = a0 + (size_t)64 * DIMC;
  const unsigned short* bsrc0 = phi_q + ((size_t)b * MDIM + m0 + row) * DIMC + c8;
  const unsigned short* bsrc1 = bsrc0 + (size_t)64 * DIMC;
  float sA = 0.f, sB = 0.f;  // scale partial dots for rows row, row+64

  for (int k0 = 0; k0 < DIMC; k0 += 32) {
    __syncthreads();
    // stage A: sum 2 bf16 split-K partials -> bf16 (kvp is L2/L3-resident)
    {
      float pa8[8], pb8[8];
      uint4 pa0 = *(const uint4*)(a0 + k0);
      uint4 pb0 = *(const uint4*)(a1 + k0);
      uint4 pa1 = *(const uint4*)(a0 + KVP_STRIDE + k0);
      uint4 pb1 = *(const uint4*)(a1 + KVP_STRIDE + k0);
      const unsigned short* ua0 = (const unsigned short*)&pa0;
      const unsigned short* ub0 = (const unsigned short*)&pb0;
      const unsigned short* ua1 = (const unsigned short*)&pa1;
      const unsigned short* ub1 = (const unsigned short*)&pb1;
#pragma unroll
      for (int j = 0; j < 8; ++j) {
        pa8[j] = bf2f(ua0[j]) + bf2f(ua1[j]);
        pb8[j] = bf2f(ub0[j]) + bf2f(ub1[j]);
      }
      unsigned int wa[4], wb[4];
#pragma unroll
      for (int j = 0; j < 4; ++j) {
        wa[j] = cvt_pk_bf16(pa8[2 * j], pa8[2 * j + 1]);
        wb[j] = cvt_pk_bf16(pb8[2 * j], pb8[2 * j + 1]);
      }
      *(uint4*)&As[row * 40 + c8] = *(const uint4*)wa;
      *(uint4*)&As[(row + 64) * 40 + c8] = *(const uint4*)wb;
    }
    // stage B: phi_q natural bf16 + running scale dot with rowsum
    {
      uint4 q0 = *(const uint4*)(bsrc0 + k0);
      uint4 q1 = *(const uint4*)(bsrc1 + k0);
      *(uint4*)&Bs[row * 40 + c8] = q0;
      *(uint4*)&Bs[(row + 64) * 40 + c8] = q1;
      const unsigned short* u0 = (const unsigned short*)&q0;
      const unsigned short* u1 = (const unsigned short*)&q1;
#pragma unroll
      for (int j = 0; j < 8; ++j) {
        const float r = rs_lds[k0 + c8 + j];
        sA += bf2f(u0[j]) * r;
        sB += bf2f(u1[j]) * r;
      }
    }
    __syncthreads();
    bf16x8 a[4], bv[4];
#pragma unroll
    for (int i = 0; i < 4; ++i)
      a[i] = *(const bf16x8*)&As[(wr * 64 + i * 16 + l15) * 40 + q * 8];
#pragma unroll
    for (int j = 0; j < 4; ++j)
      bv[j] = *(const bf16x8*)&Bs[(wc * 64 + j * 16 + l15) * 40 + q * 8];
#pragma unroll
    for (int i = 0; i < 4; ++i)
#pragma unroll
      for (int j = 0; j < 4; ++j)
        acc[i][j] =
            __builtin_amdgcn_mfma_f32_16x16x32_bf16(a[i], bv[j], acc[i][j], 0, 0, 0);
  }
  // reduce the 4 per-row scale partials and invert
  __syncthreads();
  red[row * 4 + (t & 3)] = sA;
  red[(row + 64) * 4 + (t & 3)] = sB;
  __syncthreads();
  if (t < 128) {
    float s = red[t * 4] + red[t * 4 + 1] + red[t * 4 + 2] + red[t * 4 + 3];
    scl[t] = 1.f / (s + 1e-8f);
  }
  __syncthreads();

  float* ob = out + (size_t)b * DIMC * MDIM;
#pragma unroll
  for (int j = 0; j < 4; ++j) {
    const int ml = wc * 64 + j * 16 + l15;
    const int m = m0 + ml;
    const float sc = scl[ml];
#pragma unroll
    for (int i = 0; i < 4; ++i) {
#pragma unroll
      for (int r = 0; r < 4; ++r) {
        const int d = d0 + wr * 64 + i * 16 + q * 4 + r;
        ob[(size_t)d * MDIM + m] = acc[i][j][r] * sc;
      }
    }
  }
}

extern "C" void kernel_launch(void* const* d_in, const int* in_sizes, int n_in,
                              void* d_out, int out_size, void* d_ws, size_t ws_size,
                              hipStream_t stream) {
  const float* query = (const float*)d_in[0];  // [B,256,M]
  const float* key   = (const float*)d_in[1];  // [B,256,N]
  const float* value = (const float*)d_in[2];  // [B,256,N]
  const float* W     = (const float*)d_in[3];  // [256,256]
  float* out = (float*)d_out;                  // [B,256,M]

  unsigned short* Wt    = (unsigned short*)d_ws;             // 256*256
  unsigned short* phi_q = Wt + 65536;                        // B*M*256 (m-major)
  unsigned short* phi_k = phi_q + (size_t)BSZ * MDIM * DIMC; // B*256*N (e-major)
  unsigned short* kvp   = phi_k + (size_t)BSZ * DIMC * NDIM; // 2 * B*256*256 bf16
  float* rowsum = (float*)(kvp + 2 * KVP_STRIDE);            // B*256

  hipLaunchKernelGGL(prep_kernel, dim3(256), dim3(256), 0, stream, W, Wt, rowsum);
  hipLaunchKernelGGL(phiq_kernel, dim3(MDIM / 128, DIMC / 128, BSZ), dim3(256),
                     0, stream, query, Wt, phi_q);
  hipLaunchKernelGGL(phik_kernel, dim3(NDIM / 128, DIMC / 128, BSZ), dim3(256),
                     0, stream, key, Wt, phi_k, rowsum);
  hipLaunchKernelGGL(kv_kernel, dim3(DIMC / 128, DIMC / 128, BSZ * 2), dim3(256),
                     0, stream, value, phi_k, kvp);
  hipLaunchKernelGGL(out_kernel, dim3(MDIM / 128, DIMC / 128, BSZ), dim3(256),
                     0, stream, kvp, phi_q, rowsum, out);
}